// Round 7
// baseline (368.193 us; speedup 1.0000x reference)
//
#include <hip/hip_runtime.h>
#include <hip/hip_bf16.h>
#include <math.h>

// B=4, S=2048, D=1024, H=16, DK=64. fp32 I/O. bf16 MFMA internals.

#define B_SZ   4
#define S_LEN  2048
#define D_DIM  1024
#define NH     16
#define DKD    64
#define M_TOT  (B_SZ * S_LEN)   // 8192

typedef __bf16 bf16_t;
typedef bf16_t bf16x8 __attribute__((ext_vector_type(8)));
typedef bf16_t bf16x4 __attribute__((ext_vector_type(4)));
typedef float  f32x4  __attribute__((ext_vector_type(4)));

typedef __attribute__((address_space(1))) void gvoid;
typedef __attribute__((address_space(3))) void lvoid;

extern "C" __device__ float __ocml_native_exp2_f32(float);  // single v_exp_f32

// ---------------------------------------------------------------------------
// fp32 -> bf16 convert: all four weight matrices in one launch (z selects).
// ---------------------------------------------------------------------------
__global__ __launch_bounds__(256)
void cvt4_kernel(const float* __restrict__ s0, const float* __restrict__ s1,
                 const float* __restrict__ s2, const float* __restrict__ s3,
                 bf16_t* __restrict__ d0, bf16_t* __restrict__ d1,
                 bf16_t* __restrict__ d2, bf16_t* __restrict__ d3, int n4)
{
    const int zz = blockIdx.z;
    const float* src = (zz == 0) ? s0 : (zz == 1) ? s1 : (zz == 2) ? s2 : s3;
    bf16_t*      dst = (zz == 0) ? d0 : (zz == 1) ? d1 : (zz == 2) ? d2 : d3;
    const int i = blockIdx.x * blockDim.x + threadIdx.x;
    if (i < n4) {
        f32x4 v = *(const f32x4*)(src + (size_t)i * 4);
        bf16x4 o;
        #pragma unroll
        for (int j = 0; j < 4; ++j) o[j] = (bf16_t)v[j];
        *(bf16x4*)(dst + (size_t)i * 4) = o;
    }
}

// ---------------------------------------------------------------------------
// Fused QKV projection GEMM, grid (8=cols, 64=rows, 3=z): columns fastest so
// the 8 blocks sharing one A row-tile run concurrently (A streams from HBM
// once; W stays L2-hot). BM=BN=128, BK=32. A fp32: reg-prefetch + cvt +
// ds_write; W bf16: global_load_lds width=16. z==2 writes transposed (Vt).
// ---------------------------------------------------------------------------
__global__ __launch_bounds__(256, 2)
void qkv_gemm(const float* __restrict__ Aq, const float* __restrict__ Ak,
              const float* __restrict__ Av,
              const bf16_t* __restrict__ Wqb, const bf16_t* __restrict__ Wkb,
              const bf16_t* __restrict__ Wvb,
              const float* __restrict__ bq, const float* __restrict__ bk,
              const float* __restrict__ bv,
              bf16_t* __restrict__ Qw, bf16_t* __restrict__ Kw,
              bf16_t* __restrict__ Vt, float qscale)
{
    constexpr int K = 1024, N = 1024;
    constexpr int BM = 128, BK = 32;

    __shared__ __align__(16) bf16_t lA[BM * BK];   // 8 KB
    __shared__ __align__(16) bf16_t lB[128 * BK];  // 8 KB

    const int z = blockIdx.z;
    const float* A  = (z == 0) ? Aq : (z == 1) ? Ak : Av;
    const bf16_t* W = (z == 0) ? Wqb : (z == 1) ? Wkb : Wvb;
    const float* bias = (z == 0) ? bq : (z == 1) ? bk : bv;
    const float scale = (z == 0) ? qscale : 1.0f;

    const int tid  = threadIdx.x;
    const int wave = tid >> 6;
    const int lane = tid & 63;

    const int col0 = blockIdx.x * 128;   // x = columns (fastest)
    const int row0 = blockIdx.y * BM;    // y = rows

    const int wr = (wave >> 1) * 64;
    const int wc = (wave & 1) * 64;

    f32x4 acc[4][4] = {};

    const int frow = lane & 15;
    const int kq   = (lane >> 4) * 8;

    // A staging: thread handles chunks p*256+tid (p=0,1), 8 elems each.
    const int r0c = tid >> 2;
    const int k0c = (tid & 3) * 8;
    const int r1c = (256 + tid) >> 2;

    f32x4 pa[2][2];
    {
        const float* g0 = A + (size_t)(row0 + r0c) * K + k0c;
        const float* g1 = A + (size_t)(row0 + r1c) * K + k0c;
        pa[0][0] = *(const f32x4*)g0;  pa[0][1] = *(const f32x4*)(g0 + 4);
        pa[1][0] = *(const f32x4*)g1;  pa[1][1] = *(const f32x4*)(g1 + 4);
    }

    for (int k0 = 0; k0 < K; k0 += BK) {
        __syncthreads();
        #pragma unroll
        for (int p = 0; p < 2; ++p) {
            bf16x8 a8;
            #pragma unroll
            for (int j = 0; j < 4; ++j) {
                a8[j]     = (bf16_t)pa[p][0][j];
                a8[4 + j] = (bf16_t)pa[p][1][j];
            }
            *(bf16x8*)(lA + (p * 256 + tid) * 8) = a8;
        }
        #pragma unroll
        for (int c = 0; c < 2; ++c) {
            const int chunk = c * 4 + wave;
            const int e     = chunk * 512 + lane * 8;
            const int rr    = e >> 5;
            const int kk    = e & 31;
            __builtin_amdgcn_global_load_lds((gvoid*)(W + (size_t)(col0 + rr) * K + k0 + kk),
                                             (lvoid*)(lB + chunk * 512), 16, 0, 0);
        }
        __syncthreads();

        if (k0 + BK < K) {
            const float* g0 = A + (size_t)(row0 + r0c) * K + (k0 + BK) + k0c;
            const float* g1 = A + (size_t)(row0 + r1c) * K + (k0 + BK) + k0c;
            pa[0][0] = *(const f32x4*)g0;  pa[0][1] = *(const f32x4*)(g0 + 4);
            pa[1][0] = *(const f32x4*)g1;  pa[1][1] = *(const f32x4*)(g1 + 4);
        }

        bf16x8 af[4], bfr[4];
        #pragma unroll
        for (int i = 0; i < 4; ++i) {
            af[i]  = *(const bf16x8*)(lA + (wr + i * 16 + frow) * BK + kq);
            bfr[i] = *(const bf16x8*)(lB + (wc + i * 16 + frow) * BK + kq);
        }
        #pragma unroll
        for (int i = 0; i < 4; ++i)
            #pragma unroll
            for (int j = 0; j < 4; ++j)
                acc[i][j] = __builtin_amdgcn_mfma_f32_16x16x32_bf16(af[i], bfr[j], acc[i][j], 0, 0, 0);
    }

    // C/D layout: col=lane&15, row=(lane>>4)*4+reg  [m89/m91-verified]
    const int rb   = (lane >> 4) * 4;
    const int ccol = lane & 15;
    #pragma unroll
    for (int j = 0; j < 4; ++j) {
        const int n = col0 + wc + j * 16 + ccol;
        const float bvv = bias[n];
        #pragma unroll
        for (int i = 0; i < 4; ++i) {
            const int m = row0 + wr + i * 16 + rb;
            if (z == 2) {
                bf16x4 o4;
                #pragma unroll
                for (int r = 0; r < 4; ++r) o4[r] = (bf16_t)(acc[i][j][r] + bvv);
                *(bf16x4*)(Vt + (size_t)n * M_TOT + m) = o4;   // V^T[n][m]
            } else {
                bf16_t* Cp = (z == 0) ? Qw : Kw;
                #pragma unroll
                for (int r = 0; r < 4; ++r)
                    Cp[(size_t)(m + r) * N + n] = (bf16_t)((acc[i][j][r] + bvv) * scale);
            }
        }
    }
}

// ---------------------------------------------------------------------------
// Out-projection GEMM: out_f32 = ctx_bf16 @ Wo_bf16^T + bo.
// Grid (8=cols, 64=rows); BK=32 pure global_load_lds staging.
// ---------------------------------------------------------------------------
__global__ __launch_bounds__(256, 2)
void gemm_out(const bf16_t* __restrict__ A, const bf16_t* __restrict__ Bt,
              const float* __restrict__ bias, float* __restrict__ C)
{
    constexpr int K = 1024, N = 1024;
    constexpr int BM = 128, BK = 32;

    __shared__ __align__(16) bf16_t lA[BM * BK];
    __shared__ __align__(16) bf16_t lB[128 * BK];

    const int tid  = threadIdx.x;
    const int wave = tid >> 6;
    const int lane = tid & 63;

    const int col0 = blockIdx.x * 128;
    const int row0 = blockIdx.y * BM;

    const int wr = (wave >> 1) * 64;
    const int wc = (wave & 1) * 64;

    f32x4 acc[4][4] = {};

    const int frow = lane & 15;
    const int kq   = (lane >> 4) * 8;

    for (int k0 = 0; k0 < K; k0 += BK) {
        __syncthreads();
        #pragma unroll
        for (int c = 0; c < 2; ++c) {
            const int chunk = c * 4 + wave;
            const int e     = chunk * 512 + lane * 8;
            const int r     = e >> 5;
            const int kk    = e & 31;
            __builtin_amdgcn_global_load_lds((gvoid*)(A + (size_t)(row0 + r) * K + k0 + kk),
                                             (lvoid*)(lA + chunk * 512), 16, 0, 0);
            __builtin_amdgcn_global_load_lds((gvoid*)(Bt + (size_t)(col0 + r) * K + k0 + kk),
                                             (lvoid*)(lB + chunk * 512), 16, 0, 0);
        }
        __syncthreads();

        bf16x8 af[4], bfr[4];
        #pragma unroll
        for (int i = 0; i < 4; ++i) {
            af[i]  = *(const bf16x8*)(lA + (wr + i * 16 + frow) * BK + kq);
            bfr[i] = *(const bf16x8*)(lB + (wc + i * 16 + frow) * BK + kq);
        }
        #pragma unroll
        for (int i = 0; i < 4; ++i)
            #pragma unroll
            for (int j = 0; j < 4; ++j)
                acc[i][j] = __builtin_amdgcn_mfma_f32_16x16x32_bf16(af[i], bfr[j], acc[i][j], 0, 0, 0);
    }

    const int rb   = (lane >> 4) * 4;
    const int ccol = lane & 15;
    #pragma unroll
    for (int j = 0; j < 4; ++j) {
        const int n = col0 + wc + j * 16 + ccol;
        const float bvv = bias[n];
        #pragma unroll
        for (int i = 0; i < 4; ++i) {
            const int m = row0 + wr + i * 16 + rb;
            #pragma unroll
            for (int r = 0; r < 4; ++r)
                C[(size_t)(m + r) * N + n] = acc[i][j][r] + bvv;
        }
    }
}

// ---------------------------------------------------------------------------
// MFMA flash attention (no max-tracking; Q pre-scaled by 0.125*log2e).
// XCD swizzle: all 16 q-blocks of one (b,h) land on the same XCD so the
// 4 MB K+V working set fits its 4 MB L2.
// ---------------------------------------------------------------------------
__global__ __launch_bounds__(256, 4)
void attn_mfma(const bf16_t* __restrict__ Qg, const bf16_t* __restrict__ Kg,
               const bf16_t* __restrict__ Vt, bf16_t* __restrict__ ctx)
{
    constexpr int PSTR = 72;
    __shared__ __align__(16) bf16_t lK[64 * PSTR];
    __shared__ __align__(16) bf16_t lV[64 * PSTR];
    __shared__ __align__(16) bf16_t lP[4][32 * PSTR];

    const int tid  = threadIdx.x;
    const int wave = tid >> 6;
    const int lane = tid & 63;
    const int qd   = lane >> 4;
    const int c    = lane & 15;

    const int g    = blockIdx.x;           // 0..1023
    const int bh   = ((g >> 7) << 3) | (g & 7);
    const int qblk = (g >> 3) & 15;
    const int b    = bh >> 4;
    const int h    = bh & 15;

    const int q0 = qblk * 128 + wave * 32;

    const bf16_t* Qb = Qg + ((size_t)(b * S_LEN + q0)) * D_DIM + h * DKD;
    const bf16_t* Kb = Kg + ((size_t)(b * S_LEN)) * D_DIM + h * DKD;
    const bf16_t* Vb = Vt + ((size_t)(h * DKD)) * M_TOT + b * S_LEN;

    bf16_t* Pw = &lP[wave][0];

    bf16x8 qf[2][2];
    #pragma unroll
    for (int qt = 0; qt < 2; ++qt)
        #pragma unroll
        for (int ks = 0; ks < 2; ++ks)
            qf[qt][ks] = *(const bf16x8*)(Qb + (size_t)(qt * 16 + c) * D_DIM + ks * 32 + qd * 8);

    bf16x8 ones;
    #pragma unroll
    for (int i = 0; i < 8; ++i) ones[i] = (bf16_t)1.0f;

    f32x4 oacc[4][2] = {};
    f32x4 lacc[2]    = {};

    for (int kt = 0; kt < S_LEN; kt += 64) {
        __syncthreads();
        #pragma unroll
        for (int cc = 0; cc < 2; ++cc) {
            const int ch  = cc * 256 + tid;
            const int row = ch >> 3;
            const int c8  = ch & 7;
            bf16x8 kv = *(const bf16x8*)(Kb + (size_t)(kt + row) * D_DIM + c8 * 8);
            bf16x8 vv = *(const bf16x8*)(Vb + (size_t)row * M_TOT + kt + c8 * 8);
            *(bf16x8*)(lK + row * PSTR + c8 * 8) = kv;
            *(bf16x8*)(lV + row * PSTR + c8 * 8) = vv;
        }
        __syncthreads();

        bf16x8 kf[4][2];
        #pragma unroll
        for (int i = 0; i < 4; ++i)
            #pragma unroll
            for (int ks = 0; ks < 2; ++ks)
                kf[i][ks] = *(const bf16x8*)(lK + (i * 16 + c) * PSTR + ks * 32 + qd * 8);

        f32x4 st[4][2] = {};
        #pragma unroll
        for (int ks = 0; ks < 2; ++ks)
            #pragma unroll
            for (int i = 0; i < 4; ++i)
                #pragma unroll
                for (int qt = 0; qt < 2; ++qt)
                    st[i][qt] = __builtin_amdgcn_mfma_f32_16x16x32_bf16(kf[i][ks], qf[qt][ks], st[i][qt], 0, 0, 0);

        bf16x8 vf[4][2];
        #pragma unroll
        for (int fm = 0; fm < 4; ++fm)
            #pragma unroll
            for (int ks = 0; ks < 2; ++ks)
                vf[fm][ks] = *(const bf16x8*)(lV + (fm * 16 + c) * PSTR + ks * 32 + qd * 8);

        #pragma unroll
        for (int i = 0; i < 4; ++i)
            #pragma unroll
            for (int qt = 0; qt < 2; ++qt) {
                bf16x4 pw;
                #pragma unroll
                for (int r = 0; r < 4; ++r)
                    pw[r] = (bf16_t)__ocml_native_exp2_f32(st[i][qt][r]);
                *(bf16x4*)(Pw + (qt * 16 + c) * PSTR + i * 16 + qd * 4) = pw;
            }

        #pragma unroll
        for (int qn = 0; qn < 2; ++qn)
            #pragma unroll
            for (int ks = 0; ks < 2; ++ks) {
                bf16x8 pf = *(const bf16x8*)(Pw + (qn * 16 + c) * PSTR + ks * 32 + qd * 8);
                lacc[qn] = __builtin_amdgcn_mfma_f32_16x16x32_bf16(ones, pf, lacc[qn], 0, 0, 0);
                #pragma unroll
                for (int fm = 0; fm < 4; ++fm)
                    oacc[fm][qn] = __builtin_amdgcn_mfma_f32_16x16x32_bf16(vf[fm][ks], pf, oacc[fm][qn], 0, 0, 0);
            }
    }

    #pragma unroll
    for (int qn = 0; qn < 2; ++qn) {
        const float linv = 1.0f / lacc[qn][0];
        bf16_t* op = ctx + ((size_t)(b * S_LEN + q0 + qn * 16 + c)) * D_DIM + h * DKD + qd * 4;
        #pragma unroll
        for (int fm = 0; fm < 4; ++fm) {
            bf16x4 o4;
            #pragma unroll
            for (int r = 0; r < 4; ++r) o4[r] = (bf16_t)(oacc[fm][qn][r] * linv);
            *(bf16x4*)(op + fm * 16) = o4;
        }
    }
}

// ---------------------------------------------------------------------------
extern "C" void kernel_launch(void* const* d_in, const int* in_sizes, int n_in,
                              void* d_out, int out_size, void* d_ws, size_t ws_size,
                              hipStream_t stream)
{
    const float* query = (const float*)d_in[0];
    const float* key_  = (const float*)d_in[1];
    const float* value = (const float*)d_in[2];
    const float* Wq    = (const float*)d_in[3];
    const float* bq    = (const float*)d_in[4];
    const float* Wk    = (const float*)d_in[5];
    const float* bk    = (const float*)d_in[6];
    const float* Wv    = (const float*)d_in[7];
    const float* bv    = (const float*)d_in[8];
    const float* Wo    = (const float*)d_in[9];
    const float* bo    = (const float*)d_in[10];
    float* out = (float*)d_out;

    const size_t mat  = (size_t)M_TOT * D_DIM;
    const size_t wmat = (size_t)D_DIM * D_DIM;

    // ws (bf16), 68 MB: t0 16MB (Wk'/Wv'/Wo' early; ctx later) | w0 2MB (Wq')
    //                   | Qw 16MB | Kw 16MB | Vt 16MB
    bf16_t* t0 = (bf16_t*)d_ws;
    bf16_t* w0 = t0 + mat;
    bf16_t* Qw = w0 + wmat;
    bf16_t* Kw = Qw + mat;
    bf16_t* Vt = Kw + mat;
    bf16_t* w1 = t0;                 // Wk' (inside t0; dead after qkv_gemm)
    bf16_t* w2 = t0 + wmat;          // Wv'
    bf16_t* w3 = Vt + mat;           // Wo' (persists past ctx write)

    const int gcvt_w = (int)(wmat / 4 / 256);
    const float qscale = 0.18033688011112042f;   // 0.125 * log2(e)

    cvt4_kernel<<<dim3(gcvt_w, 1, 4), 256, 0, stream>>>(
        Wq, Wk, Wv, Wo, w0, w1, w2, w3, (int)(wmat / 4));

    qkv_gemm<<<dim3(D_DIM / 128, M_TOT / 128, 3), 256, 0, stream>>>(
        query, key_, value, w0, w1, w2, bq, bk, bv, Qw, Kw, Vt, qscale);

    attn_mfma<<<dim3(B_SZ * NH * (S_LEN / 128)), 256, 0, stream>>>(Qw, Kw, Vt, t0);

    gemm_out<<<dim3(D_DIM / 128, M_TOT / 128), 256, 0, stream>>>(t0, w3, bo, out);
}